// Round 4
// baseline (3613.861 us; speedup 1.0000x reference)
//
#include <hip/hip_runtime.h>

#define T_STEPS 1024
#define BATCH   64
#define NIN     32
#define NH      256
#define NOUT    16

typedef __attribute__((ext_vector_type(8))) _Float16 half8;
typedef __attribute__((ext_vector_type(4))) _Float16 half4;
typedef __attribute__((ext_vector_type(4))) float    f32x4;

__device__ __forceinline__ float fast_tanh(float x) {
  // tanh(x) = 1 - 2/(exp2(2*log2e*x)+1); exp2->inf/0 gives correct +-1 tails
  float e = __builtin_amdgcn_exp2f(x * 2.8853900817779268f);
  return 1.0f - 2.0f * __builtin_amdgcn_rcpf(e + 1.0f);
}

// LDS layout (round-2, conflict-verified): rlds[group][buf][m][...] ushort,
// row stride 320 (40 blocks of 8); element n at blk=(n>>3)^(m&7), j=n&7;
// u (k=256..287) at blk=(32+q)^(m&7).
#define ROW 320
#define BUFSZ (16 * 320)

// Round-7: latency-hiding via INDEPENDENT co-resident recurrences.
//  - Round-3 counters showed the step is latency-bound (per-CU MfmaUtil 21%,
//    VALU 29%); 8x32 beat 4x64 purely on 2-waves/SIMD overlap, but its waves
//    share flags so stalls are correlated. Here: 2 blocks x 8 waves; waves
//    0-3 run batch-group A, waves 4-7 run group B — separate LDS buffers,
//    separate flag sets, zero coupling. Each SIMD hosts one A-wave and one
//    B-wave; A's poll/tanh-tail hides under B's MFMA issue and vice versa.
//  - z-path fully evicted from the time loop: a second trivially-parallel
//    kernel (4096 independent 16x16x256 tiles over all CUs) recomputes
//    r=tanh(x_t) from the stored f32 states and does z = r@Wout + bout.
//    Removes wave-0's 8-MFMA straggle, the z store, and the epilogue.
//  - Per-group protocol is byte-identical to the round-3-verified kernel:
//    single ballot poll on 4 flags, no s_barrier, lgkmcnt(0) before publish.

__global__ __launch_bounds__(512, 1)
void RecurrentNetwork_19628000543215_kernel(
    const float* __restrict__ inputs,  // [T][B][NIN]
    const float* __restrict__ noise,   // [T][B][NH]
    const float* __restrict__ x0,      // [B][NH]
    const float* __restrict__ Win,     // [NIN][NH]
    const float* __restrict__ Wrec,    // [NH][NH]
    const float* __restrict__ brec,    // [NH]
    float* __restrict__ outx)          // states [T][B][NH]
{
  __shared__ alignas(16) unsigned short rlds[4 * BUFSZ];  // [group][2 bufs]
  __shared__ int prodf[8];                                // [group][4 flags]
  volatile int* vflags = (volatile int*)prodf;

  const int g   = blockIdx.x;       // 0..1: batches [32g, 32g+32)
  const int tid = threadIdx.x;
  const int w   = tid >> 6;         // wave 0..7
  const int gg  = w >> 2;           // group within block (independent RNN)
  const int wl  = w & 3;            // wave within group: n-cols [64wl,64wl+64)
  const int l   = tid & 63;
  const int m   = l & 15;           // batch-in-group (B col / C col)
  const int q   = l >> 4;           // quad
  const int b   = 32 * g + 16 * gg + m;   // global batch
  const int mx  = m & 7;            // LDS swizzle key
  const int gbase = gg * (2 * BUFSZ);     // this group's LDS region
  const int fbase = 4 * gg;               // this group's flag base

  if (tid < 8) prodf[tid] = 0;

  // ---- weights -> persistent register A-frags, ALPHA pre-folded ----
  // A-frag (16x16x32): row = lane&15, k = 32*kt + 8*q + j; lane->k map only
  // has to MATCH the r/u LDS layout (contraction is permutation-invariant).
  half8 wr[4][9];                   // kt 0..7 = 0.1*Wrec^T, kt 8 = 0.1*Win^T
  #pragma unroll
  for (int nt = 0; nt < 4; ++nt) {
    const int n = 64 * wl + 16 * nt + m;
    #pragma unroll
    for (int kt = 0; kt < 9; ++kt) {
      #pragma unroll
      for (int j = 0; j < 8; ++j) {
        const int k = 32 * kt + 8 * q + j;
        const float v = (kt < 8) ? Wrec[(size_t)k * NH + n]
                                 : Win[(size_t)(k - 256) * NH + n];
        wr[nt][kt][j] = (_Float16)(0.1f * v);
      }
    }
  }

  f32x4 brecs[4], x[4];
  #pragma unroll
  for (int nt = 0; nt < 4; ++nt) {
    const int n0 = 64 * wl + 16 * nt + 4 * q;
    brecs[nt] = 0.1f * (*(const f32x4*)(brec + n0));
    x[nt]     = *(const f32x4*)(x0 + (size_t)b * NH + n0);
  }

  // ---- preloop: r_{-1}=tanh(x0), u_0 -> buf0; q_0 -> regs ----
  #pragma unroll
  for (int nt = 0; nt < 4; ++nt) {
    const int n0 = 64 * wl + 16 * nt + 4 * q;
    half4 r;
    r.x = (_Float16)fast_tanh(x[nt].x);
    r.y = (_Float16)fast_tanh(x[nt].y);
    r.z = (_Float16)fast_tanh(x[nt].z);
    r.w = (_Float16)fast_tanh(x[nt].w);
    const int blk = (n0 >> 3) ^ mx;
    *(half4*)&rlds[gbase + m * ROW + blk * 8 + (n0 & 7)] = r;
  }
  if (wl == 1) {
    const float* up = inputs + (size_t)b * NIN + 8 * q;   // t = 0
    const f32x4 ua = *(const f32x4*)up;
    const f32x4 ub = *(const f32x4*)(up + 4);
    half8 uu;
    uu[0]=(_Float16)ua.x; uu[1]=(_Float16)ua.y; uu[2]=(_Float16)ua.z; uu[3]=(_Float16)ua.w;
    uu[4]=(_Float16)ub.x; uu[5]=(_Float16)ub.y; uu[6]=(_Float16)ub.z; uu[7]=(_Float16)ub.w;
    const int blk = (32 + q) ^ mx;
    *(half8*)&rlds[gbase + m * ROW + blk * 8] = uu;
  }
  f32x4 qv[4];
  #pragma unroll
  for (int nt = 0; nt < 4; ++nt)
    qv[nt] = *(const f32x4*)(noise + (size_t)b * NH + 64 * wl + 16 * nt + 4 * q);  // q_0
  __syncthreads();

  int myfl = 0;                     // last-seen prodf[fbase + (l&3)]

  // ---- time loop ----
  #pragma unroll 1
  for (int t = 0; t < T_STEPS; ++t) {
    const int rb = gbase + (t & 1) * BUFSZ;
    const int wb = gbase + BUFSZ - (t & 1) * BUFSZ;
    const int tn = (t + 1 < T_STEPS) ? t + 1 : T_STEPS - 1;

    // single poll point: all of this group's producers done with step t-1
    while (__ballot(myfl >= t) != ~0ull) myfl = vflags[fbase + (l & 3)];
    asm volatile("" ::: "memory");  // no LDS reads hoisted above the poll

    f32x4 ua, ub;                   // wl==1: u_{t+1} load issued early
    if (wl == 1) {
      const float* up = inputs + ((size_t)tn * BATCH + b) * NIN + 8 * q;
      ua = *(const f32x4*)up;
      ub = *(const f32x4*)(up + 4);
    }
    // q_{t+1} prefetch (consumed AFTER next step's K-loop => ~1.5 steps slack)
    f32x4 qn[4];
    #pragma unroll
    for (int nt = 0; nt < 4; ++nt)
      qn[nt] = *(const f32x4*)(noise + ((size_t)tn * BATCH + b) * NH + 64 * wl + 16 * nt + 4 * q);

    // acc = 0.1*brec + r_{t-1}@(0.1*Wrec) + u_t@(0.1*Win)   [q_t added later]
    f32x4 acc[4];
    acc[0] = brecs[0]; acc[1] = brecs[1]; acc[2] = brecs[2]; acc[3] = brecs[3];

    #pragma unroll
    for (int kt = 0; kt < 9; ++kt) {
      const int blk = (4 * kt + q) ^ mx;
      const half8 bf = *(const half8*)&rlds[rb + m * ROW + blk * 8];
      acc[0] = __builtin_amdgcn_mfma_f32_16x16x32_f16(wr[0][kt], bf, acc[0], 0, 0, 0);
      acc[1] = __builtin_amdgcn_mfma_f32_16x16x32_f16(wr[1][kt], bf, acc[1], 0, 0, 0);
      acc[2] = __builtin_amdgcn_mfma_f32_16x16x32_f16(wr[2][kt], bf, acc[2], 0, 0, 0);
      acc[3] = __builtin_amdgcn_mfma_f32_16x16x32_f16(wr[3][kt], bf, acc[3], 0, 0, 0);
    }

    // x_t = 0.9*x_{t-1} + acc + q_t ; store states[t]
    #pragma unroll
    for (int nt = 0; nt < 4; ++nt) {
      x[nt] = 0.9f * x[nt] + acc[nt] + qv[nt];
      const int n0 = 64 * wl + 16 * nt + 4 * q;
      *(f32x4*)(outx + ((size_t)t * BATCH + b) * NH + n0) = x[nt];
    }

    // r_t = tanh(x_t) -> fp16 -> buf[(t+1)&1]
    #pragma unroll
    for (int nt = 0; nt < 4; ++nt) {
      const int n0 = 64 * wl + 16 * nt + 4 * q;
      half4 r;
      r.x = (_Float16)fast_tanh(x[nt].x);
      r.y = (_Float16)fast_tanh(x[nt].y);
      r.z = (_Float16)fast_tanh(x[nt].z);
      r.w = (_Float16)fast_tanh(x[nt].w);
      const int blk = (n0 >> 3) ^ mx;
      *(half4*)&rlds[wb + m * ROW + blk * 8 + (n0 & 7)] = r;
    }

    if (wl == 1) {                  // stage u_{t+1}
      half8 uu;
      uu[0]=(_Float16)ua.x; uu[1]=(_Float16)ua.y; uu[2]=(_Float16)ua.z; uu[3]=(_Float16)ua.w;
      uu[4]=(_Float16)ub.x; uu[5]=(_Float16)ub.y; uu[6]=(_Float16)ub.z; uu[7]=(_Float16)ub.w;
      const int blk = (32 + q) ^ mx;
      *(half8*)&rlds[wb + m * ROW + blk * 8] = uu;
    }

    qv[0] = qn[0]; qv[1] = qn[1]; qv[2] = qn[2]; qv[3] = qn[3];   // q_{t+1} now owned

    // publish: data drained (lgkm in-order) THEN flag
    asm volatile("s_waitcnt lgkmcnt(0)" ::: "memory");
    if (l == 0) vflags[fbase + wl] = t + 1;
    myfl = vflags[fbase + (l & 3)]; // early re-read for next step's poll
  }
}

// Phase 2: z_t = tanh(x_t) @ Wout + bout for all (t,b) — embarrassingly
// parallel over T*B/16 = 4096 independent 16-row x 16-out x 256-k tiles.
// Reads the f32 states written by phase 1 (same stream => ordered).
__global__ __launch_bounds__(256, 4)
void RecurrentNetwork_19628000543215_zkernel(
    const float* __restrict__ states,  // [T*B][NH]
    const float* __restrict__ Wout,    // [NH][NOUT]
    const float* __restrict__ bout,    // [NOUT]
    float* __restrict__ outz)          // [T*B][NOUT]
{
  const int tid  = threadIdx.x;
  const int wv   = tid >> 6;
  const int l    = tid & 63;
  const int m    = l & 15;
  const int q    = l >> 4;
  const int tile = blockIdx.x * 4 + wv;     // 0..4095
  const int row  = tile * 16 + m;           // flat (t*B + b)

  half8 wo[8];                      // Wout^T A-frags, same lane->k map
  #pragma unroll
  for (int kt = 0; kt < 8; ++kt)
    #pragma unroll
    for (int j = 0; j < 8; ++j)
      wo[kt][j] = (_Float16)Wout[(size_t)(32 * kt + 8 * q + j) * NOUT + m];

  f32x4 zac = *(const f32x4*)(bout + 4 * q);
  const float* xrow = states + (size_t)row * NH;

  #pragma unroll
  for (int kt = 0; kt < 8; ++kt) {
    const f32x4 xa = *(const f32x4*)(xrow + 32 * kt + 8 * q);
    const f32x4 xb = *(const f32x4*)(xrow + 32 * kt + 8 * q + 4);
    half8 rf;
    rf[0] = (_Float16)fast_tanh(xa.x);
    rf[1] = (_Float16)fast_tanh(xa.y);
    rf[2] = (_Float16)fast_tanh(xa.z);
    rf[3] = (_Float16)fast_tanh(xa.w);
    rf[4] = (_Float16)fast_tanh(xb.x);
    rf[5] = (_Float16)fast_tanh(xb.y);
    rf[6] = (_Float16)fast_tanh(xb.z);
    rf[7] = (_Float16)fast_tanh(xb.w);
    zac = __builtin_amdgcn_mfma_f32_16x16x32_f16(wo[kt], rf, zac, 0, 0, 0);
  }
  // C layout: col = lane&15 = row-in-tile, row = 4q+reg = nout
  *(f32x4*)(outz + (size_t)row * NOUT + 4 * q) = zac;
}

extern "C" void kernel_launch(void* const* d_in, const int* in_sizes, int n_in,
                              void* d_out, int out_size, void* d_ws, size_t ws_size,
                              hipStream_t stream) {
  (void)in_sizes; (void)n_in; (void)out_size; (void)d_ws; (void)ws_size;
  float* outz = (float*)d_out;
  float* outx = (float*)d_out + (size_t)T_STEPS * BATCH * NOUT;
  RecurrentNetwork_19628000543215_kernel<<<dim3(2), dim3(512), 0, stream>>>(
      (const float*)d_in[0],   // inputs
      (const float*)d_in[1],   // noise
      (const float*)d_in[2],   // x0
      (const float*)d_in[3],   // Win
      (const float*)d_in[4],   // Wrec
      (const float*)d_in[5],   // brec
      outx);
  RecurrentNetwork_19628000543215_zkernel<<<dim3(1024), dim3(256), 0, stream>>>(
      outx,
      (const float*)d_in[6],   // Wout
      (const float*)d_in[7],   // bout
      outz);
}

// Round 5
// 1378.069 us; speedup vs baseline: 2.6224x; 2.6224x over previous
//
#include <hip/hip_runtime.h>

#define T_STEPS 1024
#define BATCH   64
#define NIN     32
#define NH      256
#define NOUT    16

typedef __attribute__((ext_vector_type(8))) _Float16 half8;
typedef __attribute__((ext_vector_type(4))) _Float16 half4;
typedef __attribute__((ext_vector_type(4))) float    f32x4;

__device__ __forceinline__ float fast_tanh(float x) {
  // tanh(x) = 1 - 2/(exp2(2*log2e*x)+1); exp2->inf/0 gives correct +-1 tails
  float e = __builtin_amdgcn_exp2f(x * 2.8853900817779268f);
  return 1.0f - 2.0f * __builtin_amdgcn_rcpf(e + 1.0f);
}

// LDS layout (round-2, conflict-verified): rlds[buf][m][...] ushort, row
// stride 320 (40 blocks of 8); element n at blk=(n>>3)^(m&7), j=n&7;
// u (k=256..287) at blk=(32+q)^(m&7).
#define ROW 320
#define BUFSZ (16 * 320)

// Round-9: back to the PROVEN 8-wave x 32-col core (1255 us, VGPR 116) —
// the 4x64 and dual-group restructures measured slower (2950 / 7300 cyc per
// step vs 2657; round-4's VGPR_Count=128 < 144 weight regs shows the
// big-weight configs break register allocation). Three local cuts only:
//  1. z evicted from the loop (phase-2 kernel, proven round-4): SIMD0 drops
//     from 44 to 36 MFMAs/step — removes the straggler.
//  2. kt-parity accumulator chain split: 9-deep dependent MFMA chains ->
//     5/4-deep, 4 interleaved chains per wave (~130 cyc latency cut).
//  3. x-stores moved AFTER the flag publish (vmcnt-only, drain during the
//     next poll; removes 8 store issues + addressing from the pre-publish
//     critical path).
// Sync protocol byte-identical to the proven kernel: single ballot poll on
// 8 flags, no s_barrier, lgkmcnt(0) drain before flag publish.

__global__ __launch_bounds__(512, 2)
void RecurrentNetwork_19628000543215_kernel(
    const float* __restrict__ inputs,  // [T][B][NIN]
    const float* __restrict__ noise,   // [T][B][NH]
    const float* __restrict__ x0,      // [B][NH]
    const float* __restrict__ Win,     // [NIN][NH]
    const float* __restrict__ Wrec,    // [NH][NH]
    const float* __restrict__ brec,    // [NH]
    float* __restrict__ outx)          // states [T][B][NH]
{
  __shared__ alignas(16) unsigned short rlds[2 * BUFSZ];
  __shared__ int prodf[8];
  volatile int* vflags = (volatile int*)prodf;

  const int g   = blockIdx.x;       // batch group: batches [16g, 16g+16)
  const int tid = threadIdx.x;
  const int w   = tid >> 6;         // wave 0..7: owns n-columns [32w, 32w+32)
  const int l   = tid & 63;
  const int m   = l & 15;           // batch-in-group (B col / C col)
  const int q   = l >> 4;           // quad
  const int b   = 16 * g + m;       // global batch
  const int mx  = m & 7;            // LDS swizzle key

  if (tid < 8) prodf[tid] = 0;

  // ---- weights -> persistent register A-frags, ALPHA pre-folded ----
  // A-frag (16x16x32): row = lane&15, k = 32*kt + 8*q + j; lane->k map only
  // has to MATCH the r/u LDS layout (contraction is permutation-invariant).
  half8 wr[2][9];                   // kt 0..7 = 0.1*Wrec^T, kt 8 = 0.1*Win^T
  #pragma unroll
  for (int nt = 0; nt < 2; ++nt) {
    const int n = 32 * w + 16 * nt + m;
    #pragma unroll
    for (int kt = 0; kt < 9; ++kt) {
      #pragma unroll
      for (int j = 0; j < 8; ++j) {
        const int k = 32 * kt + 8 * q + j;
        const float v = (kt < 8) ? Wrec[(size_t)k * NH + n]
                                 : Win[(size_t)(k - 256) * NH + n];
        wr[nt][kt][j] = (_Float16)(0.1f * v);
      }
    }
  }

  f32x4 brecs[2], x[2];
  #pragma unroll
  for (int nt = 0; nt < 2; ++nt) {
    const int n0 = 32 * w + 16 * nt + 4 * q;
    brecs[nt] = 0.1f * (*(const f32x4*)(brec + n0));
    x[nt]     = *(const f32x4*)(x0 + (size_t)b * NH + n0);
  }

  // ---- preloop: r_{-1}=tanh(x0), u_0 -> buf0; q_0 -> regs ----
  #pragma unroll
  for (int nt = 0; nt < 2; ++nt) {
    const int n0 = 32 * w + 16 * nt + 4 * q;
    half4 r;
    r.x = (_Float16)fast_tanh(x[nt].x);
    r.y = (_Float16)fast_tanh(x[nt].y);
    r.z = (_Float16)fast_tanh(x[nt].z);
    r.w = (_Float16)fast_tanh(x[nt].w);
    const int blk = (n0 >> 3) ^ mx;
    *(half4*)&rlds[m * ROW + blk * 8 + (n0 & 7)] = r;
  }
  if (w == 1) {
    const float* up = inputs + (size_t)b * NIN + 8 * q;   // t = 0
    const f32x4 ua = *(const f32x4*)up;
    const f32x4 ub = *(const f32x4*)(up + 4);
    half8 uu;
    uu[0]=(_Float16)ua.x; uu[1]=(_Float16)ua.y; uu[2]=(_Float16)ua.z; uu[3]=(_Float16)ua.w;
    uu[4]=(_Float16)ub.x; uu[5]=(_Float16)ub.y; uu[6]=(_Float16)ub.z; uu[7]=(_Float16)ub.w;
    const int blk = (32 + q) ^ mx;
    *(half8*)&rlds[m * ROW + blk * 8] = uu;
  }
  f32x4 qv[2];
  qv[0] = *(const f32x4*)(noise + (size_t)b * NH + 32 * w + 4 * q);   // q_0
  qv[1] = *(const f32x4*)(noise + (size_t)b * NH + 32 * w + 16 + 4 * q);
  __syncthreads();

  int myfl = 0;                     // last-seen prodf[l&7]

  // ---- time loop ----
  #pragma unroll 1
  for (int t = 0; t < T_STEPS; ++t) {
    const int rb = (t & 1) * BUFSZ;
    const int wb = BUFSZ - rb;
    const int tn = (t + 1 < T_STEPS) ? t + 1 : T_STEPS - 1;

    // single poll point: all producers must have written step t-1
    while (__ballot(myfl >= t) != ~0ull) myfl = vflags[l & 7];
    asm volatile("" ::: "memory");  // no LDS reads hoisted above the poll

    f32x4 ua, ub;                   // wave 1: u_{t+1} load issued early
    if (w == 1) {
      const float* up = inputs + ((size_t)tn * BATCH + b) * NIN + 8 * q;
      ua = *(const f32x4*)up;
      ub = *(const f32x4*)(up + 4);
    }
    // q_{t+1} prefetch (consumed AFTER next step's K-loop => ~1.5 steps slack)
    f32x4 qn0 = *(const f32x4*)(noise + ((size_t)tn * BATCH + b) * NH + 32 * w + 4 * q);
    f32x4 qn1 = *(const f32x4*)(noise + ((size_t)tn * BATCH + b) * NH + 32 * w + 16 + 4 * q);

    // acc = 0.1*brec + r_{t-1}@(0.1*Wrec) + u_t@(0.1*Win)   [q_t added later]
    // kt-parity chain split: accA over kt=0,2,4,6,8; accB over kt=1,3,5,7.
    f32x4 accA[2], accB[2];
    accA[0] = brecs[0]; accA[1] = brecs[1];
    accB[0] = f32x4{0.f, 0.f, 0.f, 0.f};
    accB[1] = f32x4{0.f, 0.f, 0.f, 0.f};

    #pragma unroll
    for (int kt = 0; kt < 9; ++kt) {
      const int blk = (4 * kt + q) ^ mx;
      const half8 bf = *(const half8*)&rlds[rb + m * ROW + blk * 8];
      if (kt & 1) {
        accB[0] = __builtin_amdgcn_mfma_f32_16x16x32_f16(wr[0][kt], bf, accB[0], 0, 0, 0);
        accB[1] = __builtin_amdgcn_mfma_f32_16x16x32_f16(wr[1][kt], bf, accB[1], 0, 0, 0);
      } else {
        accA[0] = __builtin_amdgcn_mfma_f32_16x16x32_f16(wr[0][kt], bf, accA[0], 0, 0, 0);
        accA[1] = __builtin_amdgcn_mfma_f32_16x16x32_f16(wr[1][kt], bf, accA[1], 0, 0, 0);
      }
    }

    // x_t = 0.9*x_{t-1} + (accA+accB) + q_t
    x[0] = 0.9f * x[0] + (accA[0] + accB[0]) + qv[0];
    x[1] = 0.9f * x[1] + (accA[1] + accB[1]) + qv[1];

    // r_t = tanh(x_t) -> fp16 -> buf[(t+1)&1]
    #pragma unroll
    for (int nt = 0; nt < 2; ++nt) {
      const int n0 = 32 * w + 16 * nt + 4 * q;
      half4 r;
      r.x = (_Float16)fast_tanh(x[nt].x);
      r.y = (_Float16)fast_tanh(x[nt].y);
      r.z = (_Float16)fast_tanh(x[nt].z);
      r.w = (_Float16)fast_tanh(x[nt].w);
      const int blk = (n0 >> 3) ^ mx;
      *(half4*)&rlds[wb + m * ROW + blk * 8 + (n0 & 7)] = r;
    }

    if (w == 1) {                   // stage u_{t+1}
      half8 uu;
      uu[0]=(_Float16)ua.x; uu[1]=(_Float16)ua.y; uu[2]=(_Float16)ua.z; uu[3]=(_Float16)ua.w;
      uu[4]=(_Float16)ub.x; uu[5]=(_Float16)ub.y; uu[6]=(_Float16)ub.z; uu[7]=(_Float16)ub.w;
      const int blk = (32 + q) ^ mx;
      *(half8*)&rlds[wb + m * ROW + blk * 8] = uu;
    }

    // publish: data drained (lgkm in-order) THEN flag
    asm volatile("s_waitcnt lgkmcnt(0)" ::: "memory");
    if (l == 0) vflags[w] = t + 1;
    myfl = vflags[l & 7];           // early re-read for next step's poll

    // ---- post-publish: x-store (vmcnt-only, hides in next poll wait) ----
    #pragma unroll
    for (int nt = 0; nt < 2; ++nt) {
      const int n0 = 32 * w + 16 * nt + 4 * q;
      *(f32x4*)(outx + ((size_t)t * BATCH + b) * NH + n0) = x[nt];
    }
    qv[0] = qn0;                    // q_{t+1} now owned
    qv[1] = qn1;
  }
}

// Phase 2: z_t = tanh(x_t) @ Wout + bout for all (t,b) — embarrassingly
// parallel over T*B/16 = 4096 independent 16-row x 16-out x 256-k tiles.
// Reads the f32 states written by phase 1 (same stream => ordered).
__global__ __launch_bounds__(256, 4)
void RecurrentNetwork_19628000543215_zkernel(
    const float* __restrict__ states,  // [T*B][NH]
    const float* __restrict__ Wout,    // [NH][NOUT]
    const float* __restrict__ bout,    // [NOUT]
    float* __restrict__ outz)          // [T*B][NOUT]
{
  const int tid  = threadIdx.x;
  const int wv   = tid >> 6;
  const int l    = tid & 63;
  const int m    = l & 15;
  const int q    = l >> 4;
  const int tile = blockIdx.x * 4 + wv;     // 0..4095
  const int row  = tile * 16 + m;           // flat (t*B + b)

  half8 wo[8];                      // Wout^T A-frags, same lane->k map
  #pragma unroll
  for (int kt = 0; kt < 8; ++kt)
    #pragma unroll
    for (int j = 0; j < 8; ++j)
      wo[kt][j] = (_Float16)Wout[(size_t)(32 * kt + 8 * q + j) * NOUT + m];

  f32x4 zac = *(const f32x4*)(bout + 4 * q);
  const float* xrow = states + (size_t)row * NH;

  #pragma unroll
  for (int kt = 0; kt < 8; ++kt) {
    const f32x4 xa = *(const f32x4*)(xrow + 32 * kt + 8 * q);
    const f32x4 xb = *(const f32x4*)(xrow + 32 * kt + 8 * q + 4);
    half8 rf;
    rf[0] = (_Float16)fast_tanh(xa.x);
    rf[1] = (_Float16)fast_tanh(xa.y);
    rf[2] = (_Float16)fast_tanh(xa.z);
    rf[3] = (_Float16)fast_tanh(xa.w);
    rf[4] = (_Float16)fast_tanh(xb.x);
    rf[5] = (_Float16)fast_tanh(xb.y);
    rf[6] = (_Float16)fast_tanh(xb.z);
    rf[7] = (_Float16)fast_tanh(xb.w);
    zac = __builtin_amdgcn_mfma_f32_16x16x32_f16(wo[kt], rf, zac, 0, 0, 0);
  }
  // C layout: col = lane&15 = row-in-tile, row = 4q+reg = nout
  *(f32x4*)(outz + (size_t)row * NOUT + 4 * q) = zac;
}

extern "C" void kernel_launch(void* const* d_in, const int* in_sizes, int n_in,
                              void* d_out, int out_size, void* d_ws, size_t ws_size,
                              hipStream_t stream) {
  (void)in_sizes; (void)n_in; (void)out_size; (void)d_ws; (void)ws_size;
  float* outz = (float*)d_out;
  float* outx = (float*)d_out + (size_t)T_STEPS * BATCH * NOUT;
  RecurrentNetwork_19628000543215_kernel<<<dim3(4), dim3(512), 0, stream>>>(
      (const float*)d_in[0],   // inputs
      (const float*)d_in[1],   // noise
      (const float*)d_in[2],   // x0
      (const float*)d_in[3],   // Win
      (const float*)d_in[4],   // Wrec
      (const float*)d_in[5],   // brec
      outx);
  RecurrentNetwork_19628000543215_zkernel<<<dim3(1024), dim3(256), 0, stream>>>(
      outx,
      (const float*)d_in[6],   // Wout
      (const float*)d_in[7],   // bout
      outz);
}

// Round 6
// 1332.894 us; speedup vs baseline: 2.7113x; 1.0339x over previous
//
#include <hip/hip_runtime.h>

#define T_STEPS 1024
#define BATCH   64
#define NIN     32
#define NH      256
#define NOUT    16

typedef __attribute__((ext_vector_type(8))) _Float16 half8;
typedef __attribute__((ext_vector_type(4))) _Float16 half4;
typedef __attribute__((ext_vector_type(4))) float    f32x4;

__device__ __forceinline__ float fast_tanh(float x) {
  // tanh(x) = 1 - 2/(exp2(2*log2e*x)+1); exp2->inf/0 gives correct +-1 tails
  float e = __builtin_amdgcn_exp2f(x * 2.8853900817779268f);
  return 1.0f - 2.0f * __builtin_amdgcn_rcpf(e + 1.0f);
}

// LDS layout (round-2, conflict-verified): rlds[buf][m][...] ushort, row
// stride 320 (40 blocks of 8); element n at blk=(n>>3)^(m&7), j=n&7;
// u (k=256..287) at blk=(32+q)^(m&7).
#define ROW 320
#define BUFSZ (16 * 320)

// Round-10: hardware barrier instead of the LDS flag-poll protocol.
//  Round-5 falsified the compute-path theories (z-evict + chain-split +
//  store-motion all neutral; 2650 cyc/step vs ~900 cyc of modeled work,
//  per-CU MFMA 19% / VALU 30% => stall-dominated). Residual theory: the
//  software barrier (flag ds_write + multi-spin volatile poll, ~130-150
//  cyc per retry, gated by the slowest wave) is the dominant per-step
//  cost. Replaced with: s_waitcnt lgkmcnt(0) (drain LDS writes only —
//  NOT __syncthreads(), whose vmcnt(0) would serialize the HBM x-stores)
//  + s_barrier. One barrier per step suffices with the double buffer:
//  before the barrier every wave has finished reading buf[t&1] and
//  writing buf[(t+1)&1].
//  Kept from round-5 (measured neutral, structurally fine): z evicted to
//  phase-2 kernel, kt-parity chain split, x-stores after the sync point.

__global__ __launch_bounds__(512, 2)
void RecurrentNetwork_19628000543215_kernel(
    const float* __restrict__ inputs,  // [T][B][NIN]
    const float* __restrict__ noise,   // [T][B][NH]
    const float* __restrict__ x0,      // [B][NH]
    const float* __restrict__ Win,     // [NIN][NH]
    const float* __restrict__ Wrec,    // [NH][NH]
    const float* __restrict__ brec,    // [NH]
    float* __restrict__ outx)          // states [T][B][NH]
{
  __shared__ alignas(16) unsigned short rlds[2 * BUFSZ];

  const int g   = blockIdx.x;       // batch group: batches [16g, 16g+16)
  const int tid = threadIdx.x;
  const int w   = tid >> 6;         // wave 0..7: owns n-columns [32w, 32w+32)
  const int l   = tid & 63;
  const int m   = l & 15;           // batch-in-group (B col / C col)
  const int q   = l >> 4;           // quad
  const int b   = 16 * g + m;       // global batch
  const int mx  = m & 7;            // LDS swizzle key

  // ---- weights -> persistent register A-frags, ALPHA pre-folded ----
  // A-frag (16x16x32): row = lane&15, k = 32*kt + 8*q + j; lane->k map only
  // has to MATCH the r/u LDS layout (contraction is permutation-invariant).
  half8 wr[2][9];                   // kt 0..7 = 0.1*Wrec^T, kt 8 = 0.1*Win^T
  #pragma unroll
  for (int nt = 0; nt < 2; ++nt) {
    const int n = 32 * w + 16 * nt + m;
    #pragma unroll
    for (int kt = 0; kt < 9; ++kt) {
      #pragma unroll
      for (int j = 0; j < 8; ++j) {
        const int k = 32 * kt + 8 * q + j;
        const float v = (kt < 8) ? Wrec[(size_t)k * NH + n]
                                 : Win[(size_t)(k - 256) * NH + n];
        wr[nt][kt][j] = (_Float16)(0.1f * v);
      }
    }
  }

  f32x4 brecs[2], x[2];
  #pragma unroll
  for (int nt = 0; nt < 2; ++nt) {
    const int n0 = 32 * w + 16 * nt + 4 * q;
    brecs[nt] = 0.1f * (*(const f32x4*)(brec + n0));
    x[nt]     = *(const f32x4*)(x0 + (size_t)b * NH + n0);
  }

  // ---- preloop: r_{-1}=tanh(x0), u_0 -> buf0; q_0 -> regs ----
  #pragma unroll
  for (int nt = 0; nt < 2; ++nt) {
    const int n0 = 32 * w + 16 * nt + 4 * q;
    half4 r;
    r.x = (_Float16)fast_tanh(x[nt].x);
    r.y = (_Float16)fast_tanh(x[nt].y);
    r.z = (_Float16)fast_tanh(x[nt].z);
    r.w = (_Float16)fast_tanh(x[nt].w);
    const int blk = (n0 >> 3) ^ mx;
    *(half4*)&rlds[m * ROW + blk * 8 + (n0 & 7)] = r;
  }
  if (w == 1) {
    const float* up = inputs + (size_t)b * NIN + 8 * q;   // t = 0
    const f32x4 ua = *(const f32x4*)up;
    const f32x4 ub = *(const f32x4*)(up + 4);
    half8 uu;
    uu[0]=(_Float16)ua.x; uu[1]=(_Float16)ua.y; uu[2]=(_Float16)ua.z; uu[3]=(_Float16)ua.w;
    uu[4]=(_Float16)ub.x; uu[5]=(_Float16)ub.y; uu[6]=(_Float16)ub.z; uu[7]=(_Float16)ub.w;
    const int blk = (32 + q) ^ mx;
    *(half8*)&rlds[m * ROW + blk * 8] = uu;
  }
  f32x4 qv[2];
  qv[0] = *(const f32x4*)(noise + (size_t)b * NH + 32 * w + 4 * q);   // q_0
  qv[1] = *(const f32x4*)(noise + (size_t)b * NH + 32 * w + 16 + 4 * q);
  __syncthreads();

  // ---- time loop ----
  #pragma unroll 1
  for (int t = 0; t < T_STEPS; ++t) {
    const int rb = (t & 1) * BUFSZ;
    const int wb = BUFSZ - rb;
    const int tn = (t + 1 < T_STEPS) ? t + 1 : T_STEPS - 1;

    f32x4 ua, ub;                   // wave 1: u_{t+1} load issued early
    if (w == 1) {
      const float* up = inputs + ((size_t)tn * BATCH + b) * NIN + 8 * q;
      ua = *(const f32x4*)up;
      ub = *(const f32x4*)(up + 4);
    }
    // q_{t+1} prefetch (consumed AFTER this step's x-update => ~1 step slack)
    f32x4 qn0 = *(const f32x4*)(noise + ((size_t)tn * BATCH + b) * NH + 32 * w + 4 * q);
    f32x4 qn1 = *(const f32x4*)(noise + ((size_t)tn * BATCH + b) * NH + 32 * w + 16 + 4 * q);

    // acc = 0.1*brec + r_{t-1}@(0.1*Wrec) + u_t@(0.1*Win)   [q_t added later]
    // kt-parity chain split: accA over kt=0,2,4,6,8; accB over kt=1,3,5,7.
    f32x4 accA[2], accB[2];
    accA[0] = brecs[0]; accA[1] = brecs[1];
    accB[0] = f32x4{0.f, 0.f, 0.f, 0.f};
    accB[1] = f32x4{0.f, 0.f, 0.f, 0.f};

    #pragma unroll
    for (int kt = 0; kt < 9; ++kt) {
      const int blk = (4 * kt + q) ^ mx;
      const half8 bf = *(const half8*)&rlds[rb + m * ROW + blk * 8];
      if (kt & 1) {
        accB[0] = __builtin_amdgcn_mfma_f32_16x16x32_f16(wr[0][kt], bf, accB[0], 0, 0, 0);
        accB[1] = __builtin_amdgcn_mfma_f32_16x16x32_f16(wr[1][kt], bf, accB[1], 0, 0, 0);
      } else {
        accA[0] = __builtin_amdgcn_mfma_f32_16x16x32_f16(wr[0][kt], bf, accA[0], 0, 0, 0);
        accA[1] = __builtin_amdgcn_mfma_f32_16x16x32_f16(wr[1][kt], bf, accA[1], 0, 0, 0);
      }
    }

    // x_t = 0.9*x_{t-1} + (accA+accB) + q_t
    x[0] = 0.9f * x[0] + (accA[0] + accB[0]) + qv[0];
    x[1] = 0.9f * x[1] + (accA[1] + accB[1]) + qv[1];

    // r_t = tanh(x_t) -> fp16 -> buf[(t+1)&1]  (LDS writes gate the barrier:
    // keep them as early as possible, everything else after)
    #pragma unroll
    for (int nt = 0; nt < 2; ++nt) {
      const int n0 = 32 * w + 16 * nt + 4 * q;
      half4 r;
      r.x = (_Float16)fast_tanh(x[nt].x);
      r.y = (_Float16)fast_tanh(x[nt].y);
      r.z = (_Float16)fast_tanh(x[nt].z);
      r.w = (_Float16)fast_tanh(x[nt].w);
      const int blk = (n0 >> 3) ^ mx;
      *(half4*)&rlds[wb + m * ROW + blk * 8 + (n0 & 7)] = r;
    }

    if (w == 1) {                   // stage u_{t+1}
      half8 uu;
      uu[0]=(_Float16)ua.x; uu[1]=(_Float16)ua.y; uu[2]=(_Float16)ua.z; uu[3]=(_Float16)ua.w;
      uu[4]=(_Float16)ub.x; uu[5]=(_Float16)ub.y; uu[6]=(_Float16)ub.z; uu[7]=(_Float16)ub.w;
      const int blk = (32 + q) ^ mx;
      *(half8*)&rlds[wb + m * ROW + blk * 8] = uu;
    }

    qv[0] = qn0;                    // q_{t+1} now owned
    qv[1] = qn1;

    // ---- step barrier: drain LDS writes (NOT vmcnt — x-stores stay async),
    // then hardware rendezvous. Replaces the flag/poll protocol entirely.
    asm volatile("s_waitcnt lgkmcnt(0)" ::: "memory");
    __builtin_amdgcn_s_barrier();
    asm volatile("" ::: "memory");  // no next-step LDS reads hoisted above

    // ---- post-barrier: x-store (vmcnt-only, off the rendezvous path) ----
    #pragma unroll
    for (int nt = 0; nt < 2; ++nt) {
      const int n0 = 32 * w + 16 * nt + 4 * q;
      *(f32x4*)(outx + ((size_t)t * BATCH + b) * NH + n0) = x[nt];
    }
  }
}

// Phase 2: z_t = tanh(x_t) @ Wout + bout for all (t,b) — embarrassingly
// parallel over T*B/16 = 4096 independent 16-row x 16-out x 256-k tiles.
// Reads the f32 states written by phase 1 (same stream => ordered).
__global__ __launch_bounds__(256, 4)
void RecurrentNetwork_19628000543215_zkernel(
    const float* __restrict__ states,  // [T*B][NH]
    const float* __restrict__ Wout,    // [NH][NOUT]
    const float* __restrict__ bout,    // [NOUT]
    float* __restrict__ outz)          // [T*B][NOUT]
{
  const int tid  = threadIdx.x;
  const int wv   = tid >> 6;
  const int l    = tid & 63;
  const int m    = l & 15;
  const int q    = l >> 4;
  const int tile = blockIdx.x * 4 + wv;     // 0..4095
  const int row  = tile * 16 + m;           // flat (t*B + b)

  half8 wo[8];                      // Wout^T A-frags, same lane->k map
  #pragma unroll
  for (int kt = 0; kt < 8; ++kt)
    #pragma unroll
    for (int j = 0; j < 8; ++j)
      wo[kt][j] = (_Float16)Wout[(size_t)(32 * kt + 8 * q + j) * NOUT + m];

  f32x4 zac = *(const f32x4*)(bout + 4 * q);
  const float* xrow = states + (size_t)row * NH;

  #pragma unroll
  for (int kt = 0; kt < 8; ++kt) {
    const f32x4 xa = *(const f32x4*)(xrow + 32 * kt + 8 * q);
    const f32x4 xb = *(const f32x4*)(xrow + 32 * kt + 8 * q + 4);
    half8 rf;
    rf[0] = (_Float16)fast_tanh(xa.x);
    rf[1] = (_Float16)fast_tanh(xa.y);
    rf[2] = (_Float16)fast_tanh(xa.z);
    rf[3] = (_Float16)fast_tanh(xa.w);
    rf[4] = (_Float16)fast_tanh(xb.x);
    rf[5] = (_Float16)fast_tanh(xb.y);
    rf[6] = (_Float16)fast_tanh(xb.z);
    rf[7] = (_Float16)fast_tanh(xb.w);
    zac = __builtin_amdgcn_mfma_f32_16x16x32_f16(wo[kt], rf, zac, 0, 0, 0);
  }
  // C layout: col = lane&15 = row-in-tile, row = 4q+reg = nout
  *(f32x4*)(outz + (size_t)row * NOUT + 4 * q) = zac;
}

extern "C" void kernel_launch(void* const* d_in, const int* in_sizes, int n_in,
                              void* d_out, int out_size, void* d_ws, size_t ws_size,
                              hipStream_t stream) {
  (void)in_sizes; (void)n_in; (void)out_size; (void)d_ws; (void)ws_size;
  float* outz = (float*)d_out;
  float* outx = (float*)d_out + (size_t)T_STEPS * BATCH * NOUT;
  RecurrentNetwork_19628000543215_kernel<<<dim3(4), dim3(512), 0, stream>>>(
      (const float*)d_in[0],   // inputs
      (const float*)d_in[1],   // noise
      (const float*)d_in[2],   // x0
      (const float*)d_in[3],   // Win
      (const float*)d_in[4],   // Wrec
      (const float*)d_in[5],   // brec
      outx);
  RecurrentNetwork_19628000543215_zkernel<<<dim3(1024), dim3(256), 0, stream>>>(
      outx,
      (const float*)d_in[6],   // Wout
      (const float*)d_in[7],   // bout
      outz);
}

// Round 7
// 1175.334 us; speedup vs baseline: 3.0748x; 1.1341x over previous
//
#include <hip/hip_runtime.h>

#define T_STEPS 1024
#define BATCH   64
#define NIN     32
#define NH      256
#define NOUT    16

typedef __attribute__((ext_vector_type(8))) _Float16 half8;
typedef __attribute__((ext_vector_type(4))) _Float16 half4;
typedef __attribute__((ext_vector_type(4))) float    f32x4;

__device__ __forceinline__ float fast_tanh(float x) {
  // tanh(x) = 1 - 2/(exp2(2*log2e*x)+1); exp2->inf/0 gives correct +-1 tails
  float e = __builtin_amdgcn_exp2f(x * 2.8853900817779268f);
  return 1.0f - 2.0f * __builtin_amdgcn_rcpf(e + 1.0f);
}

// LDS layout (round-2, conflict-verified): rlds[buf][m][...] ushort, row
// stride 320 (40 blocks of 8); element n at blk=(n>>3)^(m&7), j=n&7;
// u (k=256..287) at blk=(32+q)^(m&7).
#define ROW 320
#define BUFSZ (16 * 320)

// Round-11: critical-path shaving on the proven 8x32 + s_barrier core.
//  1. OWN-FRAGMENT BYPASS: B-fragment kt==w is written entirely by wave w
//     (its n-range [32w,32w+32) IS k-slot kt=w). LDS is in-order within a
//     wave, so wave w ds_reads its own fragment from the write buffer
//     BEFORE the barrier (drained by the existing lgkmcnt(0)) and fires
//     kt=w MFMAs immediately post-barrier from registers — hides the
//     ~120cyc ds_read latency of the remaining 8 fragments. Per-wave
//     ROTATED kt order (own first) avoids runtime-indexing the register
//     array wr (scratch hazard); 9 LDS offsets precomputed pre-loop.
//  2. Running pointers for noise/inputs/x-store (cndmask+add64 replaces
//     per-step 64-bit mul + min-clamp select chains).
//  3. cvt_pkrtz packed f32->f16 (halves convert/pack instr count).
//  4. x-stores issued inside the lgkm drain window (vmcnt path).
//  Kept: kt-parity accumulator split, z evicted to phase-2 kernel,
//  lgkmcnt(0)+s_barrier per step (round-6 verified).

__global__ __launch_bounds__(512, 2)
void RecurrentNetwork_19628000543215_kernel(
    const float* __restrict__ inputs,  // [T][B][NIN]
    const float* __restrict__ noise,   // [T][B][NH]
    const float* __restrict__ x0,      // [B][NH]
    const float* __restrict__ Win,     // [NIN][NH]
    const float* __restrict__ Wrec,    // [NH][NH]
    const float* __restrict__ brec,    // [NH]
    float* __restrict__ outx)          // states [T][B][NH]
{
  __shared__ alignas(16) unsigned short rlds[2 * BUFSZ];

  const int g   = blockIdx.x;       // batch group: batches [16g, 16g+16)
  const int tid = threadIdx.x;
  const int w   = tid >> 6;         // wave 0..7: owns n-columns [32w, 32w+32)
  const int l   = tid & 63;
  const int m   = l & 15;           // batch-in-group (B col / C col)
  const int q   = l >> 4;           // quad
  const int b   = 16 * g + m;       // global batch
  const int mx  = m & 7;            // LDS swizzle key

  // ---- weights in ROTATED kt order: slot i holds kt=(w+i)%9; i=0 is the
  // wave's own fragment. A-frag (16x16x32): row=lane&15, k=32*kt+8*q+j.
  half8 wr[2][9];                   // kt 0..7 = 0.1*Wrec^T, kt 8 = 0.1*Win^T
  int   ldso[9];                    // LDS ushort-offset of fragment slot i
  #pragma unroll
  for (int i = 0; i < 9; ++i) {
    int kt = w + i; if (kt >= 9) kt -= 9;
    ldso[i] = m * ROW + ((((4 * kt + q) ^ mx)) << 3);
    #pragma unroll
    for (int nt = 0; nt < 2; ++nt) {
      const int n = 32 * w + 16 * nt + m;
      #pragma unroll
      for (int j = 0; j < 8; ++j) {
        const int k = 32 * kt + 8 * q + j;
        const float v = (kt < 8) ? Wrec[(size_t)k * NH + n]
                                 : Win[(size_t)(k - 256) * NH + n];
        wr[nt][i][j] = (_Float16)(0.1f * v);
      }
    }
  }

  f32x4 brecs[2], x[2];
  #pragma unroll
  for (int nt = 0; nt < 2; ++nt) {
    const int n0 = 32 * w + 16 * nt + 4 * q;
    brecs[nt] = 0.1f * (*(const f32x4*)(brec + n0));
    x[nt]     = *(const f32x4*)(x0 + (size_t)b * NH + n0);
  }

  // ---- preloop: r_{-1}=tanh(x0), u_0 -> buf0; q_0 -> regs ----
  #pragma unroll
  for (int nt = 0; nt < 2; ++nt) {
    const int n0 = 32 * w + 16 * nt + 4 * q;
    half4 r;
    r.x = (_Float16)fast_tanh(x[nt].x);
    r.y = (_Float16)fast_tanh(x[nt].y);
    r.z = (_Float16)fast_tanh(x[nt].z);
    r.w = (_Float16)fast_tanh(x[nt].w);
    const int blk = (n0 >> 3) ^ mx;
    *(half4*)&rlds[m * ROW + blk * 8 + (n0 & 7)] = r;
  }
  if (w == 1) {
    const float* up = inputs + (size_t)b * NIN + 8 * q;   // t = 0
    const f32x4 ua = *(const f32x4*)up;
    const f32x4 ub = *(const f32x4*)(up + 4);
    half8 uu;
    uu[0]=(_Float16)ua.x; uu[1]=(_Float16)ua.y; uu[2]=(_Float16)ua.z; uu[3]=(_Float16)ua.w;
    uu[4]=(_Float16)ub.x; uu[5]=(_Float16)ub.y; uu[6]=(_Float16)ub.z; uu[7]=(_Float16)ub.w;
    const int blk = (32 + q) ^ mx;
    *(half8*)&rlds[m * ROW + blk * 8] = uu;
  }
  f32x4 qv[2];
  qv[0] = *(const f32x4*)(noise + (size_t)b * NH + 32 * w + 4 * q);   // q_0
  qv[1] = *(const f32x4*)(noise + (size_t)b * NH + 32 * w + 16 + 4 * q);
  __syncthreads();

  half8 bfw = *(const half8*)&rlds[ldso[0]];   // own fragment, buf0

  // running prefetch/store pointers (avoid per-step 64-bit mul + clamp)
  const float* np = noise  + (size_t)BATCH * NH  + (size_t)b * NH  + 32 * w + 4 * q;
  const float* ip = inputs + (size_t)BATCH * NIN + (size_t)b * NIN + 8 * q;
  float*       xp = outx   + (size_t)b * NH + 32 * w + 4 * q;

  // ---- time loop ----
  #pragma unroll 1
  for (int t = 0; t < T_STEPS; ++t) {
    const int rb = (t & 1) * BUFSZ;
    const int wb = BUFSZ - rb;

    f32x4 ua, ub;                   // wave 1: u_{t+1} load issued early
    if (w == 1) {
      ua = *(const f32x4*)ip;
      ub = *(const f32x4*)(ip + 4);
    }
    // q_{t+1} prefetch (row min(t+1,1023) via gated pointer increment)
    const f32x4 qn0 = *(const f32x4*)np;
    const f32x4 qn1 = *(const f32x4*)(np + 16);

    // acc = 0.1*brec + r_{t-1}@(0.1*Wrec) + u_t@(0.1*Win)   [q_t added later]
    // kt-parity chain split over rotated slots; slot 0 = own frag from regs.
    f32x4 accA[2], accB[2];
    accA[0] = brecs[0]; accA[1] = brecs[1];
    accB[0] = f32x4{0.f, 0.f, 0.f, 0.f};
    accB[1] = f32x4{0.f, 0.f, 0.f, 0.f};

    accA[0] = __builtin_amdgcn_mfma_f32_16x16x32_f16(wr[0][0], bfw, accA[0], 0, 0, 0);
    accA[1] = __builtin_amdgcn_mfma_f32_16x16x32_f16(wr[1][0], bfw, accA[1], 0, 0, 0);
    #pragma unroll
    for (int i = 1; i < 9; ++i) {
      const half8 bf = *(const half8*)&rlds[rb + ldso[i]];
      if (i & 1) {
        accB[0] = __builtin_amdgcn_mfma_f32_16x16x32_f16(wr[0][i], bf, accB[0], 0, 0, 0);
        accB[1] = __builtin_amdgcn_mfma_f32_16x16x32_f16(wr[1][i], bf, accB[1], 0, 0, 0);
      } else {
        accA[0] = __builtin_amdgcn_mfma_f32_16x16x32_f16(wr[0][i], bf, accA[0], 0, 0, 0);
        accA[1] = __builtin_amdgcn_mfma_f32_16x16x32_f16(wr[1][i], bf, accA[1], 0, 0, 0);
      }
    }

    // x_t = 0.9*x_{t-1} + (accA+accB) + q_t
    x[0] = 0.9f * x[0] + (accA[0] + accB[0]) + qv[0];
    x[1] = 0.9f * x[1] + (accA[1] + accB[1]) + qv[1];

    // r_t = tanh(x_t) -> fp16 (packed cvt) -> buf[(t+1)&1]
    #pragma unroll
    for (int nt = 0; nt < 2; ++nt) {
      const int n0 = 32 * w + 16 * nt + 4 * q;
      half4 r;
#if __has_builtin(__builtin_amdgcn_cvt_pkrtz)
      {
        auto plo = __builtin_amdgcn_cvt_pkrtz(fast_tanh(x[nt].x), fast_tanh(x[nt].y));
        auto phi = __builtin_amdgcn_cvt_pkrtz(fast_tanh(x[nt].z), fast_tanh(x[nt].w));
        r.x = plo.x; r.y = plo.y; r.z = phi.x; r.w = phi.y;
      }
#else
      r.x = (_Float16)fast_tanh(x[nt].x);
      r.y = (_Float16)fast_tanh(x[nt].y);
      r.z = (_Float16)fast_tanh(x[nt].z);
      r.w = (_Float16)fast_tanh(x[nt].w);
#endif
      const int blk = (n0 >> 3) ^ mx;
      *(half4*)&rlds[wb + m * ROW + blk * 8 + (n0 & 7)] = r;
    }

    if (w == 1) {                   // stage u_{t+1}
      half8 uu;
      uu[0]=(_Float16)ua.x; uu[1]=(_Float16)ua.y; uu[2]=(_Float16)ua.z; uu[3]=(_Float16)ua.w;
      uu[4]=(_Float16)ub.x; uu[5]=(_Float16)ub.y; uu[6]=(_Float16)ub.z; uu[7]=(_Float16)ub.w;
      const int blk = (32 + q) ^ mx;
      *(half8*)&rlds[wb + m * ROW + blk * 8] = uu;
    }

    // own-fragment self-read for step t+1 (wave-local bytes of wb; LDS is
    // in-order within a wave => sees our writes above; drained by the
    // lgkmcnt(0) below, so next step starts with bfw already in regs)
    asm volatile("" ::: "memory");  // keep this read below the writes
    bfw = *(const half8*)&rlds[wb + ldso[0]];

    // x-store + pointer bumps fill the lgkm drain window (vmcnt path)
    *(f32x4*)(xp)      = x[0];
    *(f32x4*)(xp + 16) = x[1];
    qv[0] = qn0; qv[1] = qn1;
    const bool adv = (t <= T_STEPS - 3);
    np += adv ? (size_t)(BATCH * NH)  : (size_t)0;
    ip += adv ? (size_t)(BATCH * NIN) : (size_t)0;
    xp += (size_t)(BATCH * NH);

    // step rendezvous: drain LDS (NOT vmcnt — x-stores stay async), barrier
    asm volatile("s_waitcnt lgkmcnt(0)" ::: "memory");
    __builtin_amdgcn_s_barrier();
    asm volatile("" ::: "memory");  // no next-step LDS reads hoisted above
  }
}

// Phase 2: z_t = tanh(x_t) @ Wout + bout for all (t,b) — embarrassingly
// parallel over T*B/16 = 4096 independent 16-row x 16-out x 256-k tiles.
// Reads the f32 states written by phase 1 (same stream => ordered).
__global__ __launch_bounds__(256, 4)
void RecurrentNetwork_19628000543215_zkernel(
    const float* __restrict__ states,  // [T*B][NH]
    const float* __restrict__ Wout,    // [NH][NOUT]
    const float* __restrict__ bout,    // [NOUT]
    float* __restrict__ outz)          // [T*B][NOUT]
{
  const int tid  = threadIdx.x;
  const int wv   = tid >> 6;
  const int l    = tid & 63;
  const int m    = l & 15;
  const int q    = l >> 4;
  const int tile = blockIdx.x * 4 + wv;     // 0..4095
  const int row  = tile * 16 + m;           // flat (t*B + b)

  half8 wo[8];                      // Wout^T A-frags, same lane->k map
  #pragma unroll
  for (int kt = 0; kt < 8; ++kt)
    #pragma unroll
    for (int j = 0; j < 8; ++j)
      wo[kt][j] = (_Float16)Wout[(size_t)(32 * kt + 8 * q + j) * NOUT + m];

  f32x4 zac = *(const f32x4*)(bout + 4 * q);
  const float* xrow = states + (size_t)row * NH;

  #pragma unroll
  for (int kt = 0; kt < 8; ++kt) {
    const f32x4 xa = *(const f32x4*)(xrow + 32 * kt + 8 * q);
    const f32x4 xb = *(const f32x4*)(xrow + 32 * kt + 8 * q + 4);
    half8 rf;
    rf[0] = (_Float16)fast_tanh(xa.x);
    rf[1] = (_Float16)fast_tanh(xa.y);
    rf[2] = (_Float16)fast_tanh(xa.z);
    rf[3] = (_Float16)fast_tanh(xa.w);
    rf[4] = (_Float16)fast_tanh(xb.x);
    rf[5] = (_Float16)fast_tanh(xb.y);
    rf[6] = (_Float16)fast_tanh(xb.z);
    rf[7] = (_Float16)fast_tanh(xb.w);
    zac = __builtin_amdgcn_mfma_f32_16x16x32_f16(wo[kt], rf, zac, 0, 0, 0);
  }
  // C layout: col = lane&15 = row-in-tile, row = 4q+reg = nout
  *(f32x4*)(outz + (size_t)row * NOUT + 4 * q) = zac;
}

extern "C" void kernel_launch(void* const* d_in, const int* in_sizes, int n_in,
                              void* d_out, int out_size, void* d_ws, size_t ws_size,
                              hipStream_t stream) {
  (void)in_sizes; (void)n_in; (void)out_size; (void)d_ws; (void)ws_size;
  float* outz = (float*)d_out;
  float* outx = (float*)d_out + (size_t)T_STEPS * BATCH * NOUT;
  RecurrentNetwork_19628000543215_kernel<<<dim3(4), dim3(512), 0, stream>>>(
      (const float*)d_in[0],   // inputs
      (const float*)d_in[1],   // noise
      (const float*)d_in[2],   // x0
      (const float*)d_in[3],   // Win
      (const float*)d_in[4],   // Wrec
      (const float*)d_in[5],   // brec
      outx);
  RecurrentNetwork_19628000543215_zkernel<<<dim3(1024), dim3(256), 0, stream>>>(
      outx,
      (const float*)d_in[6],   // Wout
      (const float*)d_in[7],   // bout
      outz);
}